// Round 4
// baseline (544.153 us; speedup 1.0000x reference)
//
#include <hip/hip_runtime.h>

#define NT 512
#define NWAVE 8
#define PE 136     // WxT pitch: 80 rows(h) x 128 cols(e) + pad
#define PW1 88     // W1T pitch: 48 rows(j) x 80 cols(h)
#define PH 88      // h0 pitch: 32 rows(t) x 80 cols(h)
#define UPB 7      // 32-row units per batch = ceil(200/32)

typedef __attribute__((ext_vector_type(8))) short short8;   // 8 x bf16
typedef __attribute__((ext_vector_type(4))) float f32x4;    // MFMA accumulator

__device__ __forceinline__ unsigned short f2b(float f) {
  unsigned int x = __float_as_uint(f);
  return (unsigned short)((x + 0x7fffu + ((x >> 16) & 1u)) >> 16);
}
__device__ __forceinline__ float sigmoidf(float x) {
  return __builtin_amdgcn_rcpf(1.0f + __expf(-x));
}
__device__ __forceinline__ short8 pack8(float4 a, float4 b) {
  short8 r;
  r[0] = (short)f2b(a.x); r[1] = (short)f2b(a.y); r[2] = (short)f2b(a.z); r[3] = (short)f2b(a.w);
  r[4] = (short)f2b(b.x); r[5] = (short)f2b(b.y); r[6] = (short)f2b(b.z); r[7] = (short)f2b(b.w);
  return r;
}
__device__ __forceinline__ short8 pack8q(float4 a, float4 b, float4 qa, float4 qb) {
  short8 r;
  r[0] = (short)f2b(a.x * qa.x); r[1] = (short)f2b(a.y * qa.y);
  r[2] = (short)f2b(a.z * qa.z); r[3] = (short)f2b(a.w * qa.w);
  r[4] = (short)f2b(b.x * qb.x); r[5] = (short)f2b(b.y * qb.y);
  r[6] = (short)f2b(b.z * qb.z); r[7] = (short)f2b(b.w * qb.w);
  return r;
}

// ---- precompute C[b][h] = b0[h] + sum_e q[b][e] * (W0a + W0c)[e][h] ----
__global__ __launch_bounds__(256, 2) void prep_c(
    const float* __restrict__ q, const float* __restrict__ W0,
    const float* __restrict__ b0, float* __restrict__ C, int B)
{
  __shared__ float Wac[64 * 80];
  __shared__ float qlds[32 * 64];
  const int bbase = blockIdx.x * 32, tid = threadIdx.x;
  for (int idx = tid; idx < 5120; idx += 256) {
    const int e = idx / 80, h = idx - e * 80;
    Wac[idx] = W0[e * 80 + h] + W0[(128 + e) * 80 + h];
  }
  for (int idx = tid; idx < 2048; idx += 256) {
    const int bl = idx >> 6, e = idx & 63;
    const int bg = bbase + bl;
    qlds[idx] = (bg < B) ? q[bg * 64 + e] : 0.0f;
  }
  __syncthreads();
  #pragma unroll
  for (int i = 0; i < 10; ++i) {
    const int idx = tid + i * 256;  // < 2560 = 32*80
    const int bl = idx / 80, h = idx - bl * 80;
    const int bg = bbase + bl;
    if (bg < B) {
      float acc = b0[h];
      #pragma unroll 8
      for (int e = 0; e < 64; ++e) acc += qlds[bl * 64 + e] * Wac[e * 80 + h];
      C[bg * 80 + h] = acc;
    }
  }
}

// ---- build compact worklist of real (batch, 32-row-unit) pairs ----
__global__ void build_wl(const int* __restrict__ klen, unsigned* __restrict__ hdr,
                         unsigned* __restrict__ wl, int B)
{
  const int b = blockIdx.x * 256 + threadIdx.x;
  if (b < B) {
    int L = klen[b];
    L = max(0, min(200, L));
    const int nu = (L + 31) >> 5;
    for (int u = 0; u < nu; ++u) {
      const unsigned pos = atomicAdd(&hdr[0], 1u);
      wl[pos] = ((unsigned)u << 16) | (unsigned)b;
    }
  }
}

// ---- main: persistent waves, compact-worklist stealing, cross-unit prefetch ----
// 512 blocks x 8 waves = 4096 waves, 2 blocks/CU (LDS 73.5 KB), 16 waves/CU.
// Per 32-row unit: set0 keys prefetched LAST unit (HBM latency hidden under a
// full unit of compute); set1 keys issued before L1; next unit's keys/Cpre
// issued right after the single refill readfirstlane (placed where ~nothing is
// in flight). Scores never leave the lane that needs them: butterfly leaves
// each lane its quad's 4 row-scores; epilogue is float4 per lane + 8 shfl_xor
// + 4 atomicAdds from 16 lanes. No barriers after the prologue.
__global__ __launch_bounds__(NT, 2) void din_attn_main(
    const float* __restrict__ q,
    const float* __restrict__ keys,
    const int* __restrict__ klen,
    const float* __restrict__ W0,
    const float* __restrict__ b0,
    const float* __restrict__ W1,
    const float* __restrict__ b1,
    const float* __restrict__ W2,
    const float* __restrict__ b2,
    float* __restrict__ out,
    const float* __restrict__ Cpre,
    unsigned* __restrict__ hdr,          // [0]=worklist count, [32]=pop counter
    const unsigned* __restrict__ wl,
    int B)
{
  __shared__ __align__(16) unsigned short WxT[80 * PE];        // 21760 B [h][e]
  __shared__ __align__(16) unsigned short W1T[48 * PW1];       //  8448 B [j][h]
  __shared__ __align__(16) unsigned short h0s[NWAVE][32 * PH]; // 45056 B per-wave [t][h]

  const int tid = threadIdx.x;

  // Wx[e][h]: e<64 -> W0b - W0c ; e in [64,128) -> W0d  (stored transposed)
  for (int idx = tid; idx < 128 * 80; idx += NT) {
    const int e = idx / 80, h = idx - e * 80;
    const float v = (e < 64)
        ? (W0[(64 + e) * 80 + h] - W0[(128 + e) * 80 + h])
        : W0[(128 + e) * 80 + h];
    WxT[h * PE + e] = f2b(v);
  }
  for (int idx = tid; idx < 48 * PW1; idx += NT) {
    const int j = idx / PW1, h = idx - j * PW1;
    W1T[idx] = (j < 40 && h < 80) ? f2b(W1[h * 40 + j]) : (unsigned short)0;
  }
  __syncthreads();   // the ONLY block-wide barrier

  const int wv = __builtin_amdgcn_readfirstlane(tid >> 6);
  const int lane = tid & 63;
  const int lm = lane & 15;
  const int quad = lane >> 4;
  const int gw = blockIdx.x * NWAVE + wv;
  unsigned short* h0 = h0s[wv];
  const bool dyn = (hdr != nullptr);
  unsigned* pop = dyn ? (hdr + 32) : nullptr;

  float b1v[3], w2v[3];
  #pragma unroll
  for (int nt = 0; nt < 3; ++nt) {
    const int col = nt * 16 + lm;
    b1v[nt] = (col < 40) ? b1[col] : 0.0f;
    w2v[nt] = (col < 40) ? W2[col] : 0.0f;
  }
  const float b2v = b2[0];
  const short8 z8 = {0, 0, 0, 0, 0, 0, 0, 0};

  // prefetch slot s into the given registers (keys set0, Cpre row, klen)
  auto pf = [&](int s, int& pb, int& pu, int& pL,
                float4& K0, float4& K1, float4& K2, float4& K3,
                float& C0, float& C1, float& C2, float& C3, float& C4) {
    int b, u;
    if (dyn) { const unsigned e = wl[s]; b = (int)(e & 0xFFFFu); u = (int)(e >> 16); }
    else     { b = gw; u = s - gw * UPB; }
    pb = b; pu = u;
    pL = klen[b];                      // per-lane load of a uniform value
    if (Cpre != nullptr) {
      const float* cp = Cpre + (size_t)b * 80 + lm;
      C0 = cp[0]; C1 = cp[16]; C2 = cp[32]; C3 = cp[48]; C4 = cp[64];
    } else {                           // slow fallback (no workspace)
      C0 = b0[lm]; C1 = b0[16 + lm]; C2 = b0[32 + lm]; C3 = b0[48 + lm]; C4 = b0[64 + lm];
      for (int e = 0; e < 64; ++e) {
        const float qv = q[(size_t)b * 64 + e];
        C0 += qv * (W0[e * 80 + lm] + W0[(128 + e) * 80 + lm]);
        C1 += qv * (W0[e * 80 + 16 + lm] + W0[(128 + e) * 80 + 16 + lm]);
        C2 += qv * (W0[e * 80 + 32 + lm] + W0[(128 + e) * 80 + 32 + lm]);
        C3 += qv * (W0[e * 80 + 48 + lm] + W0[(128 + e) * 80 + 48 + lm]);
        C4 += qv * (W0[e * 80 + 64 + lm] + W0[(128 + e) * 80 + 64 + lm]);
      }
    }
    const int t = min(u * 32 + lm, 199);   // clamp: garbage masked at pack
    const float4* kp = (const float4*)(keys + (size_t)b * 12800 + (size_t)t * 64);
    K0 = kp[quad * 2]; K1 = kp[quad * 2 + 1];
    K2 = kp[8 + quad * 2]; K3 = kp[8 + quad * 2 + 1];
  };

  // ---- acquire first slot ----
  int s, nwl;
  if (dyn) {
    unsigned v0 = 0u;
    if (lane == 0) v0 = atomicAdd(pop, 1u);
    s = (int)__builtin_amdgcn_readfirstlane((int)v0);
    nwl = (int)__builtin_amdgcn_readfirstlane((int)hdr[0]);
  } else {
    s = gw * UPB;
    nwl = (gw < B) ? (gw * UPB + UPB) : s;   // guard gw >= B
  }

  int cb = 0, cu = 0, cL = 0;
  float4 ck0, ck1, ck2, ck3;
  float cc0 = 0, cc1 = 0, cc2 = 0, cc3 = 0, cc4 = 0;
  if (s < nwl) pf(s, cb, cu, cL, ck0, ck1, ck2, ck3, cc0, cc1, cc2, cc3, cc4);
  unsigned vp = 0u;
  if (dyn && lane == 0) vp = atomicAdd(pop, 1u);

  while (s < nwl) {
    // q for current batch (small, L1/L2-hot; loaded at use to cap registers)
    const float4* q4p = (const float4*)(q + (size_t)cb * 64);
    const float4 q0 = q4p[quad * 2], q1 = q4p[quad * 2 + 1];
    const float4 q2v = q4p[8 + quad * 2], q3v = q4p[8 + quad * 2 + 1];

    const int Ls = max(0, min(200, __builtin_amdgcn_readfirstlane(cL)));
    const int t0 = cu << 5;

    // ---- pack set0 (consumes prefetched keys; invalid rows -> zero) ----
    const bool v0ok = (t0 + lm) < Ls;
    short8 a0 = pack8(ck0, ck1), a1 = pack8(ck2, ck3);
    short8 aq0 = pack8q(ck0, ck1, q0, q1), aq1 = pack8q(ck2, ck3, q2v, q3v);
    if (!v0ok) { a0 = z8; a1 = z8; aq0 = z8; aq1 = z8; }

    // ---- refill point: only the pending atomic is in flight here ----
    int s2;
    if (dyn) {
      s2 = (int)__builtin_amdgcn_readfirstlane((int)vp);
      if (lane == 0) vp = atomicAdd(pop, 1u);
    } else {
      s2 = s + 1;
    }

    // ---- set1 key loads (current unit), then next-unit prefetch ----
    const bool twoS = (Ls - t0) > 16;
    float4 e0, e1, e2, e3;
    if (twoS) {
      const int t1 = min(t0 + 16 + lm, 199);
      const float4* kp = (const float4*)(keys + (size_t)cb * 12800 + (size_t)t1 * 64);
      e0 = kp[quad * 2]; e1 = kp[quad * 2 + 1];
      e2 = kp[8 + quad * 2]; e3 = kp[8 + quad * 2 + 1];
    }
    int nb = 0, nu_ = 0, nL = 0;
    float4 nk0, nk1, nk2, nk3;
    float nc0 = 0, nc1 = 0, nc2 = 0, nc3 = 0, nc4 = 0;
    if (s2 < nwl) pf(s2, nb, nu_, nL, nk0, nk1, nk2, nk3, nc0, nc1, nc2, nc3, nc4);

    // ---- pack set1 ----
    short8 c0 = z8, c1 = z8, cq0 = z8, cq1 = z8;
    if (twoS) {
      const bool v1ok = (t0 + 16 + lm) < Ls;
      c0 = pack8(e0, e1); c1 = pack8(e2, e3);
      cq0 = pack8q(e0, e1, q0, q1); cq1 = pack8q(e2, e3, q2v, q3v);
      if (!v1ok) { c0 = z8; c1 = z8; cq0 = z8; cq1 = z8; }
    }

    // ---- layer 1: both sets share one weight-fragment read per nt ----
    #pragma unroll
    for (int nt = 0; nt < 5; ++nt) {
      const int col = nt * 16 + lm;
      const float cv = (nt == 0) ? cc0 : (nt == 1) ? cc1 : (nt == 2) ? cc2 : (nt == 3) ? cc3 : cc4;
      const unsigned short* wr = &WxT[col * PE + quad * 8];
      const short8 w0 = *(const short8*)(wr);
      const short8 w1 = *(const short8*)(wr + 32);
      const short8 w2 = *(const short8*)(wr + 64);
      const short8 w3 = *(const short8*)(wr + 96);
      f32x4 acc;
      acc[0] = cv; acc[1] = cv; acc[2] = cv; acc[3] = cv;
      acc = __builtin_amdgcn_mfma_f32_16x16x32_bf16(a0,  w0, acc, 0, 0, 0);
      acc = __builtin_amdgcn_mfma_f32_16x16x32_bf16(a1,  w1, acc, 0, 0, 0);
      acc = __builtin_amdgcn_mfma_f32_16x16x32_bf16(aq0, w2, acc, 0, 0, 0);
      acc = __builtin_amdgcn_mfma_f32_16x16x32_bf16(aq1, w3, acc, 0, 0, 0);
      #pragma unroll
      for (int r = 0; r < 4; ++r)
        h0[(quad * 4 + r) * PH + col] = f2b(sigmoidf(acc[r]));
      if (twoS) {
        f32x4 ac2;
        ac2[0] = cv; ac2[1] = cv; ac2[2] = cv; ac2[3] = cv;
        ac2 = __builtin_amdgcn_mfma_f32_16x16x32_bf16(c0,  w0, ac2, 0, 0, 0);
        ac2 = __builtin_amdgcn_mfma_f32_16x16x32_bf16(c1,  w1, ac2, 0, 0, 0);
        ac2 = __builtin_amdgcn_mfma_f32_16x16x32_bf16(cq0, w2, ac2, 0, 0, 0);
        ac2 = __builtin_amdgcn_mfma_f32_16x16x32_bf16(cq1, w3, ac2, 0, 0, 0);
        #pragma unroll
        for (int r = 0; r < 4; ++r)
          h0[(16 + quad * 4 + r) * PH + col] = f2b(sigmoidf(ac2[r]));
      }
    }

    // ---- layer 2+3: intra-wave h0 roundtrip; K=80 via masked quad ----
    const short8 ha00 = *(const short8*)&h0[lm * PH + quad * 8];
    const short8 ha01 = *(const short8*)&h0[lm * PH + 32 + quad * 8];
    short8 ha02 = z8;
    if (quad < 2) ha02 = *(const short8*)&h0[lm * PH + 64 + quad * 8];
    short8 ha10 = z8, ha11 = z8, ha12 = z8;
    if (twoS) {
      ha10 = *(const short8*)&h0[(16 + lm) * PH + quad * 8];
      ha11 = *(const short8*)&h0[(16 + lm) * PH + 32 + quad * 8];
      if (quad < 2) ha12 = *(const short8*)&h0[(16 + lm) * PH + 64 + quad * 8];
    }
    float pd0[4] = {0, 0, 0, 0}, pd1[4] = {0, 0, 0, 0};
    #pragma unroll
    for (int nt = 0; nt < 3; ++nt) {
      const int col = nt * 16 + lm;
      const unsigned short* wr = &W1T[col * PW1 + quad * 8];
      const short8 wb0 = *(const short8*)(wr);
      const short8 wb1 = *(const short8*)(wr + 32);
      short8 wb2 = z8;
      if (quad < 2) wb2 = *(const short8*)(wr + 64);
      f32x4 acc;
      acc[0] = b1v[nt]; acc[1] = b1v[nt]; acc[2] = b1v[nt]; acc[3] = b1v[nt];
      acc = __builtin_amdgcn_mfma_f32_16x16x32_bf16(ha00, wb0, acc, 0, 0, 0);
      acc = __builtin_amdgcn_mfma_f32_16x16x32_bf16(ha01, wb1, acc, 0, 0, 0);
      acc = __builtin_amdgcn_mfma_f32_16x16x32_bf16(ha02, wb2, acc, 0, 0, 0);
      #pragma unroll
      for (int r = 0; r < 4; ++r) pd0[r] += sigmoidf(acc[r]) * w2v[nt];
      if (twoS) {
        f32x4 ac2;
        ac2[0] = b1v[nt]; ac2[1] = b1v[nt]; ac2[2] = b1v[nt]; ac2[3] = b1v[nt];
        ac2 = __builtin_amdgcn_mfma_f32_16x16x32_bf16(ha10, wb0, ac2, 0, 0, 0);
        ac2 = __builtin_amdgcn_mfma_f32_16x16x32_bf16(ha11, wb1, ac2, 0, 0, 0);
        ac2 = __builtin_amdgcn_mfma_f32_16x16x32_bf16(ha12, wb2, ac2, 0, 0, 0);
        #pragma unroll
        for (int r = 0; r < 4; ++r) pd1[r] += sigmoidf(ac2[r]) * w2v[nt];
      }
    }
    #pragma unroll
    for (int r = 0; r < 4; ++r) {
      pd0[r] += __shfl_xor(pd0[r], 1);
      pd0[r] += __shfl_xor(pd0[r], 2);
      pd0[r] += __shfl_xor(pd0[r], 4);
      pd0[r] += __shfl_xor(pd0[r], 8);
    }
    if (twoS) {
      #pragma unroll
      for (int r = 0; r < 4; ++r) {
        pd1[r] += __shfl_xor(pd1[r], 1);
        pd1[r] += __shfl_xor(pd1[r], 2);
        pd1[r] += __shfl_xor(pd1[r], 4);
        pd1[r] += __shfl_xor(pd1[r], 8);
      }
    }
    // scores stay in-lane: lane (quad,lm) owns rows t0+4*quad+r (+16)
    float sc0[4], sc1[4];
    #pragma unroll
    for (int r = 0; r < 4; ++r) {
      const int ta = t0 + 4 * quad + r;
      sc0[r] = (ta < Ls) ? sigmoidf(pd0[r] + b2v) : 0.0f;
      sc1[r] = (twoS && (ta + 16) < Ls) ? sigmoidf(pd1[r] + b2v) : 0.0f;
    }

    // ---- epilogue: lane (quad,lm) covers e=4lm..4lm+3 over its 4(+4) rows ----
    const float* kb = keys + (size_t)cb * 12800;
    float4 w4 = {0.0f, 0.0f, 0.0f, 0.0f};
    #pragma unroll
    for (int r = 0; r < 4; ++r) {
      const int ta = t0 + 4 * quad + r;
      const float4 kva = *(const float4*)(kb + (size_t)min(ta, 199) * 64 + 4 * lm);
      w4.x += sc0[r] * kva.x; w4.y += sc0[r] * kva.y;
      w4.z += sc0[r] * kva.z; w4.w += sc0[r] * kva.w;
      if (twoS) {
        const float4 kvb = *(const float4*)(kb + (size_t)min(ta + 16, 199) * 64 + 4 * lm);
        w4.x += sc1[r] * kvb.x; w4.y += sc1[r] * kvb.y;
        w4.z += sc1[r] * kvb.z; w4.w += sc1[r] * kvb.w;
      }
    }
    // reduce across the 4 quads (xor 16, 32), then 16 lanes commit
    w4.x += __shfl_xor(w4.x, 16); w4.y += __shfl_xor(w4.y, 16);
    w4.z += __shfl_xor(w4.z, 16); w4.w += __shfl_xor(w4.w, 16);
    w4.x += __shfl_xor(w4.x, 32); w4.y += __shfl_xor(w4.y, 32);
    w4.z += __shfl_xor(w4.z, 32); w4.w += __shfl_xor(w4.w, 32);
    if (lane < 16) {
      float* op = out + (size_t)cb * 64 + 4 * lm;
      atomicAdd(op + 0, w4.x); atomicAdd(op + 1, w4.y);
      atomicAdd(op + 2, w4.z); atomicAdd(op + 3, w4.w);
    }

    // ---- rotate prefetched state ----
    cb = nb; cu = nu_; cL = nL;
    ck0 = nk0; ck1 = nk1; ck2 = nk2; ck3 = nk3;
    cc0 = nc0; cc1 = nc1; cc2 = nc2; cc3 = nc3; cc4 = nc4;
    s = s2;
  }
}

extern "C" void kernel_launch(void* const* d_in, const int* in_sizes, int n_in,
                              void* d_out, int out_size, void* d_ws, size_t ws_size,
                              hipStream_t stream) {
  const int B = in_sizes[2];
  const size_t csize = (size_t)B * 80 * sizeof(float);
  const size_t wlbytes = (size_t)B * UPB * sizeof(unsigned);

  const float* Cpre = nullptr;
  unsigned* hdr = nullptr;
  unsigned* wl = nullptr;
  size_t off = 0;
  if (ws_size >= csize) { Cpre = (const float*)d_ws; off = csize; }
  off = (off + 127) & ~(size_t)127;
  if (ws_size >= off + 256 + wlbytes) {
    hdr = (unsigned*)((char*)d_ws + off);
    wl = hdr + 64;                       // worklist right after the 256 B header
    hipMemsetAsync(hdr, 0, 256, stream);
  }
  hipMemsetAsync(d_out, 0, (size_t)out_size, stream);

  if (hdr != nullptr) {
    build_wl<<<(B + 255) / 256, 256, 0, stream>>>(
        (const int*)d_in[2], hdr, wl, B);
  }
  if (Cpre != nullptr) {
    prep_c<<<(B + 31) / 32, 256, 0, stream>>>(
        (const float*)d_in[0], (const float*)d_in[3], (const float*)d_in[4],
        (float*)d_ws, B);
  }
  din_attn_main<<<(B + NWAVE - 1) / NWAVE, NT, 0, stream>>>(
      (const float*)d_in[0], (const float*)d_in[1], (const int*)d_in[2],
      (const float*)d_in[3], (const float*)d_in[4], (const float*)d_in[5],
      (const float*)d_in[6], (const float*)d_in[7], (const float*)d_in[8],
      (float*)d_out, Cpre, hdr, (const unsigned*)wl, B);
}

// Round 5
// 381.869 us; speedup vs baseline: 1.4250x; 1.4250x over previous
//
#include <hip/hip_runtime.h>

#define NT 512
#define NWAVE 8
#define PE 136     // WxT pitch: 80 rows(h) x 128 cols(e) + pad
#define PW1 88     // W1T pitch: 48 rows(j) x 80 cols(h)
#define PH 88      // h0 pitch: 32 rows(t) x 80 cols(h)

typedef __attribute__((ext_vector_type(8))) short short8;   // 8 x bf16
typedef __attribute__((ext_vector_type(4))) float f32x4;    // MFMA accumulator

__device__ __forceinline__ unsigned short f2b(float f) {
  unsigned int x = __float_as_uint(f);
  return (unsigned short)((x + 0x7fffu + ((x >> 16) & 1u)) >> 16);
}
__device__ __forceinline__ float sigmoidf(float x) {
  return __builtin_amdgcn_rcpf(1.0f + __expf(-x));
}
__device__ __forceinline__ short8 pack8(float4 a, float4 b) {
  short8 r;
  r[0] = (short)f2b(a.x); r[1] = (short)f2b(a.y); r[2] = (short)f2b(a.z); r[3] = (short)f2b(a.w);
  r[4] = (short)f2b(b.x); r[5] = (short)f2b(b.y); r[6] = (short)f2b(b.z); r[7] = (short)f2b(b.w);
  return r;
}
__device__ __forceinline__ short8 pack8q(float4 a, float4 b, float4 qa, float4 qb) {
  short8 r;
  r[0] = (short)f2b(a.x * qa.x); r[1] = (short)f2b(a.y * qa.y);
  r[2] = (short)f2b(a.z * qa.z); r[3] = (short)f2b(a.w * qa.w);
  r[4] = (short)f2b(b.x * qb.x); r[5] = (short)f2b(b.y * qb.y);
  r[6] = (short)f2b(b.z * qb.z); r[7] = (short)f2b(b.w * qb.w);
  return r;
}

// ---- precompute C[b][h] = b0[h] + sum_e q[b][e] * (W0a + W0c)[e][h] ----
__global__ __launch_bounds__(256, 2) void prep_c(
    const float* __restrict__ q, const float* __restrict__ W0,
    const float* __restrict__ b0, float* __restrict__ C, int B)
{
  __shared__ float Wac[64 * 80];
  __shared__ float qlds[32 * 64];
  const int bbase = blockIdx.x * 32, tid = threadIdx.x;
  for (int idx = tid; idx < 5120; idx += 256) {
    const int e = idx / 80, h = idx - e * 80;
    Wac[idx] = W0[e * 80 + h] + W0[(128 + e) * 80 + h];
  }
  for (int idx = tid; idx < 2048; idx += 256) {
    const int bl = idx >> 6, e = idx & 63;
    const int bg = bbase + bl;
    qlds[idx] = (bg < B) ? q[bg * 64 + e] : 0.0f;
  }
  __syncthreads();
  #pragma unroll
  for (int i = 0; i < 10; ++i) {
    const int idx = tid + i * 256;  // < 2560 = 32*80
    const int bl = idx / 80, h = idx - bl * 80;
    const int bg = bbase + bl;
    if (bg < B) {
      float acc = b0[h];
      #pragma unroll 8
      for (int e = 0; e < 64; ++e) acc += qlds[bl * 64 + e] * Wac[e * 80 + h];
      C[bg * 80 + h] = acc;
    }
  }
}

// ---- main: static wave-per-batch, 32-row units, pipelined loads, ----
// ---- in-lane scores, register float4 epilogue, one store per batch ----
// 512 blocks x 8 waves, 2 blocks/CU (LDS 75.3 KB), 16 waves/CU.
// Per unit: set0 keys prefetched last unit; set1 + next-unit set0 issued
// back-to-back before compute (both in flight under L1/L2 MFMA); shared
// weight-fragment reads serve both 16-row sets; ONE lgkmcnt-full-wait per
// 32 rows (h0 roundtrip). Scores stay in the lane that consumes them
// (butterfly leaves every lane the sum); epilogue: 8 L1-hot float4 loads +
// FMA into a float4 register accumulator; single coalesced float4 store
// per batch at the end (no atomics, no out memset).
__global__ __launch_bounds__(NT, 2) void din_attn_main(
    const float* __restrict__ q,
    const float* __restrict__ keys,
    const int* __restrict__ klen,
    const float* __restrict__ W0,
    const float* __restrict__ b0,
    const float* __restrict__ W1,
    const float* __restrict__ b1,
    const float* __restrict__ W2,
    const float* __restrict__ b2,
    float* __restrict__ out,
    const float* __restrict__ Cpre,
    int B)
{
  __shared__ __align__(16) unsigned short WxT[80 * PE];        // 21760 B [h][e]
  __shared__ __align__(16) unsigned short W1T[48 * PW1];       //  8448 B [j][h]
  __shared__ __align__(16) unsigned short h0s[NWAVE][32 * PH]; // 45056 B per-wave [t][h]

  const int tid = threadIdx.x;

  // Wx[e][h]: e<64 -> W0b - W0c ; e in [64,128) -> W0d  (stored transposed)
  for (int idx = tid; idx < 128 * 80; idx += NT) {
    const int e = idx / 80, h = idx - e * 80;
    const float v = (e < 64)
        ? (W0[(64 + e) * 80 + h] - W0[(128 + e) * 80 + h])
        : W0[(128 + e) * 80 + h];
    WxT[h * PE + e] = f2b(v);
  }
  for (int idx = tid; idx < 48 * PW1; idx += NT) {
    const int j = idx / PW1, h = idx - j * PW1;
    W1T[idx] = (j < 40 && h < 80) ? f2b(W1[h * 40 + j]) : (unsigned short)0;
  }
  __syncthreads();   // the ONLY block-wide barrier

  const int wv = __builtin_amdgcn_readfirstlane(tid >> 6);
  const int lane = tid & 63;
  const int lm = lane & 15;
  const int quad = lane >> 4;
  const int b = blockIdx.x * NWAVE + wv;
  unsigned short* h0 = h0s[wv];
  const short8 z8 = {0, 0, 0, 0, 0, 0, 0, 0};

  if (b < B) {
    int L = klen[b];
    L = __builtin_amdgcn_readfirstlane(max(0, min(200, L)));
    const int nu = (L + 31) >> 5;

    // per-batch constants, hoisted once (q frags, folded bias, L2/L3 consts)
    const float4* q4p = (const float4*)(q + (size_t)b * 64);
    const float4 q0 = q4p[quad * 2], q1 = q4p[quad * 2 + 1];
    const float4 q2 = q4p[8 + quad * 2], q3 = q4p[8 + quad * 2 + 1];

    float cfv[5];
    if (Cpre != nullptr) {
      #pragma unroll
      for (int nt = 0; nt < 5; ++nt) cfv[nt] = Cpre[b * 80 + nt * 16 + lm];
    } else {  // slow fallback (no workspace)
      #pragma unroll
      for (int nt = 0; nt < 5; ++nt) cfv[nt] = b0[nt * 16 + lm];
      for (int e = 0; e < 64; ++e) {
        const float qv = q[(size_t)b * 64 + e];
        #pragma unroll
        for (int nt = 0; nt < 5; ++nt)
          cfv[nt] += qv * (W0[e * 80 + nt * 16 + lm] + W0[(128 + e) * 80 + nt * 16 + lm]);
      }
    }
    float b1v[3], w2v[3];
    #pragma unroll
    for (int nt = 0; nt < 3; ++nt) {
      const int col = nt * 16 + lm;
      b1v[nt] = (col < 40) ? b1[col] : 0.0f;
      w2v[nt] = (col < 40) ? W2[col] : 0.0f;
    }
    const float b2v = b2[0];

    const float* kb = keys + (size_t)b * 12800;
    float4 w4 = {0.0f, 0.0f, 0.0f, 0.0f};

    // prefetch unit 0 set0 (rows lm)
    float4 pk0, pk1, pk2, pk3;
    if (nu > 0) {
      const float4* kp = (const float4*)(kb + (size_t)min(lm, 199) * 64);
      pk0 = kp[quad * 2]; pk1 = kp[quad * 2 + 1];
      pk2 = kp[8 + quad * 2]; pk3 = kp[8 + quad * 2 + 1];
    }

    for (int u = 0; u < nu; ++u) {
      const int t0 = u << 5;
      const bool twoS = (L - t0) > 16;     // wave-uniform

      // ---- pack set0 from prefetched regs ----
      short8 a0 = pack8(pk0, pk1), a1 = pack8(pk2, pk3);
      short8 aq0 = pack8q(pk0, pk1, q0, q1), aq1 = pack8q(pk2, pk3, q2, q3);
      if (!((t0 + lm) < L)) { a0 = z8; a1 = z8; aq0 = z8; aq1 = z8; }

      // ---- issue set1 loads, then next-unit set0 prefetch (both in flight) ----
      float4 e0, e1, e2, e3;
      if (twoS) {
        const float4* kp = (const float4*)(kb + (size_t)min(t0 + 16 + lm, 199) * 64);
        e0 = kp[quad * 2]; e1 = kp[quad * 2 + 1];
        e2 = kp[8 + quad * 2]; e3 = kp[8 + quad * 2 + 1];
      }
      if (u + 1 < nu) {
        const float4* kp = (const float4*)(kb + (size_t)min(t0 + 32 + lm, 199) * 64);
        pk0 = kp[quad * 2]; pk1 = kp[quad * 2 + 1];
        pk2 = kp[8 + quad * 2]; pk3 = kp[8 + quad * 2 + 1];
      }

      // ---- pack set1 (waits only on e-regs; prefetch stays outstanding) ----
      short8 c0 = z8, c1 = z8, cq0 = z8, cq1 = z8;
      if (twoS) {
        c0 = pack8(e0, e1); c1 = pack8(e2, e3);
        cq0 = pack8q(e0, e1, q0, q1); cq1 = pack8q(e2, e3, q2, q3);
        if (!((t0 + 16 + lm) < L)) { c0 = z8; c1 = z8; cq0 = z8; cq1 = z8; }
      }

      // ---- layer 1: both sets share one weight-fragment read per nt ----
      __builtin_amdgcn_s_setprio(1);
      #pragma unroll
      for (int nt = 0; nt < 5; ++nt) {
        const int col = nt * 16 + lm;
        const unsigned short* wr = &WxT[col * PE + quad * 8];
        const short8 w0 = *(const short8*)(wr);
        const short8 w1 = *(const short8*)(wr + 32);
        const short8 w2 = *(const short8*)(wr + 64);
        const short8 w3 = *(const short8*)(wr + 96);
        f32x4 acc;
        acc[0] = cfv[nt]; acc[1] = cfv[nt]; acc[2] = cfv[nt]; acc[3] = cfv[nt];
        acc = __builtin_amdgcn_mfma_f32_16x16x32_bf16(a0,  w0, acc, 0, 0, 0);
        acc = __builtin_amdgcn_mfma_f32_16x16x32_bf16(a1,  w1, acc, 0, 0, 0);
        acc = __builtin_amdgcn_mfma_f32_16x16x32_bf16(aq0, w2, acc, 0, 0, 0);
        acc = __builtin_amdgcn_mfma_f32_16x16x32_bf16(aq1, w3, acc, 0, 0, 0);
        #pragma unroll
        for (int r = 0; r < 4; ++r)
          h0[(quad * 4 + r) * PH + col] = f2b(sigmoidf(acc[r]));
        if (twoS) {
          f32x4 ac2;
          ac2[0] = cfv[nt]; ac2[1] = cfv[nt]; ac2[2] = cfv[nt]; ac2[3] = cfv[nt];
          ac2 = __builtin_amdgcn_mfma_f32_16x16x32_bf16(c0,  w0, ac2, 0, 0, 0);
          ac2 = __builtin_amdgcn_mfma_f32_16x16x32_bf16(c1,  w1, ac2, 0, 0, 0);
          ac2 = __builtin_amdgcn_mfma_f32_16x16x32_bf16(cq0, w2, ac2, 0, 0, 0);
          ac2 = __builtin_amdgcn_mfma_f32_16x16x32_bf16(cq1, w3, ac2, 0, 0, 0);
          #pragma unroll
          for (int r = 0; r < 4; ++r)
            h0[(16 + quad * 4 + r) * PH + col] = f2b(sigmoidf(ac2[r]));
        }
      }
      __builtin_amdgcn_s_setprio(0);

      // ---- layer 2+3: ONE full h0 wait per 32 rows; K=80 via masked quad ----
      const short8 ha00 = *(const short8*)&h0[lm * PH + quad * 8];
      const short8 ha01 = *(const short8*)&h0[lm * PH + 32 + quad * 8];
      short8 ha02 = z8;
      if (quad < 2) ha02 = *(const short8*)&h0[lm * PH + 64 + quad * 8];
      short8 ha10 = z8, ha11 = z8, ha12 = z8;
      if (twoS) {
        ha10 = *(const short8*)&h0[(16 + lm) * PH + quad * 8];
        ha11 = *(const short8*)&h0[(16 + lm) * PH + 32 + quad * 8];
        if (quad < 2) ha12 = *(const short8*)&h0[(16 + lm) * PH + 64 + quad * 8];
      }
      float pd0[4] = {0, 0, 0, 0}, pd1[4] = {0, 0, 0, 0};
      __builtin_amdgcn_s_setprio(1);
      #pragma unroll
      for (int nt = 0; nt < 3; ++nt) {
        const int col = nt * 16 + lm;
        const unsigned short* wr = &W1T[col * PW1 + quad * 8];
        const short8 wb0 = *(const short8*)(wr);
        const short8 wb1 = *(const short8*)(wr + 32);
        short8 wb2 = z8;
        if (quad < 2) wb2 = *(const short8*)(wr + 64);
        f32x4 acc;
        acc[0] = b1v[nt]; acc[1] = b1v[nt]; acc[2] = b1v[nt]; acc[3] = b1v[nt];
        acc = __builtin_amdgcn_mfma_f32_16x16x32_bf16(ha00, wb0, acc, 0, 0, 0);
        acc = __builtin_amdgcn_mfma_f32_16x16x32_bf16(ha01, wb1, acc, 0, 0, 0);
        acc = __builtin_amdgcn_mfma_f32_16x16x32_bf16(ha02, wb2, acc, 0, 0, 0);
        #pragma unroll
        for (int r = 0; r < 4; ++r) pd0[r] += sigmoidf(acc[r]) * w2v[nt];
        if (twoS) {
          f32x4 ac2;
          ac2[0] = b1v[nt]; ac2[1] = b1v[nt]; ac2[2] = b1v[nt]; ac2[3] = b1v[nt];
          ac2 = __builtin_amdgcn_mfma_f32_16x16x32_bf16(ha10, wb0, ac2, 0, 0, 0);
          ac2 = __builtin_amdgcn_mfma_f32_16x16x32_bf16(ha11, wb1, ac2, 0, 0, 0);
          ac2 = __builtin_amdgcn_mfma_f32_16x16x32_bf16(ha12, wb2, ac2, 0, 0, 0);
          #pragma unroll
          for (int r = 0; r < 4; ++r) pd1[r] += sigmoidf(ac2[r]) * w2v[nt];
        }
      }
      __builtin_amdgcn_s_setprio(0);

      #pragma unroll
      for (int r = 0; r < 4; ++r) {
        pd0[r] += __shfl_xor(pd0[r], 1);
        pd0[r] += __shfl_xor(pd0[r], 2);
        pd0[r] += __shfl_xor(pd0[r], 4);
        pd0[r] += __shfl_xor(pd0[r], 8);
      }
      if (twoS) {
        #pragma unroll
        for (int r = 0; r < 4; ++r) {
          pd1[r] += __shfl_xor(pd1[r], 1);
          pd1[r] += __shfl_xor(pd1[r], 2);
          pd1[r] += __shfl_xor(pd1[r], 4);
          pd1[r] += __shfl_xor(pd1[r], 8);
        }
      }
      // scores in-lane: lane (quad,lm) owns rows t0+4*quad+r (+16)
      float sc0[4], sc1[4];
      #pragma unroll
      for (int r = 0; r < 4; ++r) {
        const int ta = t0 + 4 * quad + r;
        sc0[r] = (ta < L) ? sigmoidf(pd0[r] + b2v) : 0.0f;
        sc1[r] = (twoS && (ta + 16) < L) ? sigmoidf(pd1[r] + b2v) : 0.0f;
      }

      // ---- epilogue: lane covers e=4lm..4lm+3 over its 4(+4) rows ----
      // (rows were just read by the A-loads -> L1-hot; loads independent)
      #pragma unroll
      for (int r = 0; r < 4; ++r) {
        const int ta = t0 + 4 * quad + r;
        const float4 kva = *(const float4*)(kb + (size_t)min(ta, 199) * 64 + 4 * lm);
        w4.x += sc0[r] * kva.x; w4.y += sc0[r] * kva.y;
        w4.z += sc0[r] * kva.z; w4.w += sc0[r] * kva.w;
        if (twoS) {
          const float4 kvb = *(const float4*)(kb + (size_t)min(ta + 16, 199) * 64 + 4 * lm);
          w4.x += sc1[r] * kvb.x; w4.y += sc1[r] * kvb.y;
          w4.z += sc1[r] * kvb.z; w4.w += sc1[r] * kvb.w;
        }
      }
    }

    // ---- once per batch: reduce across quads, single coalesced store ----
    w4.x += __shfl_xor(w4.x, 16); w4.y += __shfl_xor(w4.y, 16);
    w4.z += __shfl_xor(w4.z, 16); w4.w += __shfl_xor(w4.w, 16);
    w4.x += __shfl_xor(w4.x, 32); w4.y += __shfl_xor(w4.y, 32);
    w4.z += __shfl_xor(w4.z, 32); w4.w += __shfl_xor(w4.w, 32);
    if (lane < 16)
      *(float4*)(out + (size_t)b * 64 + 4 * lm) = w4;
  }
}

extern "C" void kernel_launch(void* const* d_in, const int* in_sizes, int n_in,
                              void* d_out, int out_size, void* d_ws, size_t ws_size,
                              hipStream_t stream) {
  const int B = in_sizes[2];
  const float* Cpre = nullptr;
  if (ws_size >= (size_t)B * 80 * sizeof(float)) {
    float* C = (float*)d_ws;
    prep_c<<<(B + 31) / 32, 256, 0, stream>>>(
        (const float*)d_in[0], (const float*)d_in[3], (const float*)d_in[4], C, B);
    Cpre = C;
  }
  din_attn_main<<<(B + NWAVE - 1) / NWAVE, NT, 0, stream>>>(
      (const float*)d_in[0], (const float*)d_in[1], (const int*)d_in[2],
      (const float*)d_in[3], (const float*)d_in[4], (const float*)d_in[5],
      (const float*)d_in[6], (const float*)d_in[7], (const float*)d_in[8],
      (float*)d_out, Cpre, B);
}